// Round 9
// baseline (149.862 us; speedup 1.0000x reference)
//
#include <hip/hip_runtime.h>
#include <hip/hip_bf16.h>
#include <hip/hip_fp16.h>

// out[bn,e] = relu(relu(hp[bn]+ep[e]+b1) @ W2 + b2) @ W3 + b3
// R13: attack the TCP/MFMA parity (64-row blocks stream 640KB through L1 per
// 9933 MFMA-cycles -> both pipes ~40%). Block = 128 rows x 512 cols, full-K
// x1 in 128KB LDS with R4's proven XOR layout, f16 datapath, R4's exact wave
// shape (acc[4][8], j-fan 8, depth-2 B ping-pong), K stagger KEPT (R8 dropped
// it -> 256 CUs lockstep-hammered identical L2 lines; suspected cause of its
// unexplained stall). 1024 blocks x 512 thr, 1 block/CU, 2 waves/SIMD.
// TCP/MFMA ratio: 0.55 vs R11's 1.0.

typedef __attribute__((ext_vector_type(8))) _Float16 f16x8;  // 8 f16 (4 VGPR)
typedef __attribute__((ext_vector_type(4))) float f32x4;     // MFMA acc

static __device__ __forceinline__ ushort2 pk_f16(float a, float b) {
  union { __half2 h; ushort2 u; } c;
  c.h = __float22half2_rn(make_float2(a, b));
  return c.u;
}

// ---------------- fused prep (352 blocks x 256 thr) ----------------
// blocks 0..255  : hpb rows (2/blk)  hpb[r][k] = f16(sum_h h[r][h]*W1[h][k] + b1[k])
// blocks 256..287: epb rows (8/blk)  epb[e][k] = f16(sum_d e[e][d]*W1[256+d][k])
// blocks 288..351: w2f pack (64x64 W2 tile -> f16 B-frag records)
//   record(jg,ks): lane l holds W2[k = ks*32+(l>>4)*8 + u][col = jg*16+(l&15)], u=0..7
__global__ __launch_bounds__(256) void k_prep(
    const float* __restrict__ h_all, const float* __restrict__ e_feat,
    const float* __restrict__ W1, const float* __restrict__ b1,
    const float* __restrict__ W2,
    unsigned short* __restrict__ hpb, unsigned short* __restrict__ epb,
    unsigned short* __restrict__ w2f) {
  __shared__ float sm[64 * 68];   // 17408 B, reused per role
  const int t = threadIdx.x;
  const int b = blockIdx.x;

  if (b < 256) {                      // ---- hp part: 2 rows, f16 out
    const int r0 = b * 2;
    float (*hs)[256] = (float(*)[256])sm;
    hs[0][t] = h_all[(size_t)r0 * 256 + t];
    hs[1][t] = h_all[(size_t)(r0 + 1) * 256 + t];
    __syncthreads();
    float2 a0 = make_float2(0.f, 0.f), a1 = make_float2(0.f, 0.f);
    #pragma unroll 2
    for (int k = 0; k < 256; k += 4) {
      float2 w0 = *(const float2*)(W1 + (size_t)k * 512 + 2 * t);
      float2 w1 = *(const float2*)(W1 + (size_t)(k + 1) * 512 + 2 * t);
      float2 w2v = *(const float2*)(W1 + (size_t)(k + 2) * 512 + 2 * t);
      float2 w3v = *(const float2*)(W1 + (size_t)(k + 3) * 512 + 2 * t);
      float h00 = hs[0][k], h01 = hs[0][k + 1], h02 = hs[0][k + 2], h03 = hs[0][k + 3];
      float h10 = hs[1][k], h11 = hs[1][k + 1], h12 = hs[1][k + 2], h13 = hs[1][k + 3];
      a0.x = fmaf(h00, w0.x, a0.x); a0.y = fmaf(h00, w0.y, a0.y);
      a1.x = fmaf(h10, w0.x, a1.x); a1.y = fmaf(h10, w0.y, a1.y);
      a0.x = fmaf(h01, w1.x, a0.x); a0.y = fmaf(h01, w1.y, a0.y);
      a1.x = fmaf(h11, w1.x, a1.x); a1.y = fmaf(h11, w1.y, a1.y);
      a0.x = fmaf(h02, w2v.x, a0.x); a0.y = fmaf(h02, w2v.y, a0.y);
      a1.x = fmaf(h12, w2v.x, a1.x); a1.y = fmaf(h12, w2v.y, a1.y);
      a0.x = fmaf(h03, w3v.x, a0.x); a0.y = fmaf(h03, w3v.y, a0.y);
      a1.x = fmaf(h13, w3v.x, a1.x); a1.y = fmaf(h13, w3v.y, a1.y);
    }
    float2 bv = *(const float2*)(b1 + 2 * t);
    *(ushort2*)(hpb + (size_t)r0 * 512 + 2 * t) = pk_f16(a0.x + bv.x, a0.y + bv.y);
    *(ushort2*)(hpb + (size_t)(r0 + 1) * 512 + 2 * t) = pk_f16(a1.x + bv.x, a1.y + bv.y);
  } else if (b < 288) {               // ---- ep part: 8 rows, f16 out
    const int r0 = (b - 256) * 8;
    sm[t] = e_feat[(size_t)r0 * 64 + t];
    sm[256 + t] = e_feat[(size_t)r0 * 64 + 256 + t];
    __syncthreads();
    float2 acc[8];
    #pragma unroll
    for (int i = 0; i < 8; ++i) acc[i] = make_float2(0.f, 0.f);
    for (int k = 0; k < 64; ++k) {
      float2 wv = *(const float2*)(W1 + (size_t)(256 + k) * 512 + 2 * t);
      #pragma unroll
      for (int i = 0; i < 8; ++i) {
        acc[i].x = fmaf(sm[i * 64 + k], wv.x, acc[i].x);
        acc[i].y = fmaf(sm[i * 64 + k], wv.y, acc[i].y);
      }
    }
    #pragma unroll
    for (int i = 0; i < 8; ++i)
      *(ushort2*)(epb + (size_t)(r0 + i) * 512 + 2 * t) = pk_f16(acc[i].x, acc[i].y);
  } else {                            // ---- w2f pack
    const int bb = b - 288;           // 0..63
    const int k0 = (bb >> 3) * 64;
    const int c0 = (bb & 7) * 64;
    #pragma unroll
    for (int rr = 0; rr < 4; ++rr) {
      const int row = rr * 16 + (t >> 4);
      float4 v = *(const float4*)(W2 + (size_t)(k0 + row) * 512 + c0 + (t & 15) * 4);
      *(float4*)(&sm[row * 68 + (t & 15) * 4]) = v;
    }
    __syncthreads();
    #pragma unroll
    for (int s2 = 0; s2 < 2; ++s2) {
      const int s = t * 2 + s2;       // 0..511 (8 records x 64 lanes)
      const int rec = s >> 6, l = s & 63;
      const int jg = (c0 >> 4) + (rec & 3);
      const int ksg = (k0 >> 5) + (rec >> 2);
      const int cl = (rec & 3) * 16 + (l & 15);
      const int kl = (rec >> 2) * 32 + (l >> 4) * 8;
      union { ushort2 o[4]; uint4 v; } u;
      #pragma unroll
      for (int uu = 0; uu < 4; ++uu)
        u.o[uu] = pk_f16(sm[(kl + 2 * uu) * 68 + cl], sm[(kl + 2 * uu + 1) * 68 + cl]);
      *(uint4*)(w2f + ((size_t)(jg * 16 + ksg) * 64 + l) * 8) = u.v;
    }
  }
}

// ---------------- main fused kernel ----------------
// 1024 blocks x 512 thr (8 waves, 1 blk/CU, 2 waves/SIMD). Block = 128 rows
// (one bn, e-half) x 512 cols. Wave w: rg = w>>2 (rows rg*64..+64),
// cg = w&3 (cols cg*128..+128, j=0..7) — R4's exact per-wave shape.
// x1s: 128 rows x 512 f16, XOR layout chunk' = chunk ^ (row&7). K stagger kept.
__global__ __launch_bounds__(512, 2) void k_main(
    const unsigned short* __restrict__ hpb, const unsigned short* __restrict__ epb,
    const unsigned short* __restrict__ w2f, const float* __restrict__ b2,
    const float* __restrict__ W3, const float* __restrict__ b3,
    float* __restrict__ out) {
  __shared__ unsigned short x1s[128 * 512];   // 128 KiB, XOR-swizzled 16B chunks

  const int t = threadIdx.x;
  const int lane = t & 63;
  const int w = t >> 6;            // 0..7
  const int l15 = lane & 15, l4 = lane >> 4;
  const int rg = w >> 2;           // row group: rows rg*64 .. +64
  const int cg = w & 3;            // col group: cols cg*128 .. +128
  const int bn = blockIdx.x >> 1;
  const int e0 = (blockIdx.x & 1) << 7;      // e-half (128 rows)
  const int off = (blockIdx.x * 11) & 15;    // K stagger (kept!)
  const unsigned short* hprow = hpb + (size_t)bn * 512;

  // b-frag ping-pong; wave's col group cg -> jg = cg*8 .. +8
  const unsigned short* wrec = w2f + (size_t)cg * 65536 + (size_t)lane * 8;
  f16x8 bb[2][8];
  #pragma unroll
  for (int j = 0; j < 8; ++j) {
    bb[0][j] = *(const f16x8*)(wrec + j * 8192 + (size_t)off * 512);
    bb[1][j] = *(const f16x8*)(wrec + j * 8192 + (size_t)((off + 1) & 15) * 512);
  }

  // ---- stage x1 once: relu(hp + ep) -> f16 (packed), chunk' = chunk ^ (r&7)
  {
    const int kk = t & 63;          // 16B-chunk index (8 f16)
    const int rbase = t >> 6;       // 0..7
    const f16x8 fz = {0, 0, 0, 0, 0, 0, 0, 0};
    const f16x8 hv = *(const f16x8*)(hprow + kk * 8);
    #pragma unroll 4
    for (int rr = 0; rr < 16; ++rr) {
      const int r = rr * 8 + rbase;
      f16x8 ev = *(const f16x8*)(epb + (size_t)(e0 + r) * 512 + kk * 8);
      f16x8 x = hv + ev;
      x = __builtin_elementwise_max(x, fz);
      *(f16x8*)(&x1s[r * 512 + (kk ^ (r & 7)) * 8]) = x;
    }
  }
  __syncthreads();

  f32x4 acc[4][8] = {};
  #pragma unroll 4
  for (int ks = 0; ks < 16; ++ks) {
    const int cur = ks & 1;
    const int kr = (ks + off) & 15;        // this iter's k-slot
    const int kr2 = (ks + 2 + off) & 15;   // prefetch slot (wraps: dummy reload)
    f16x8 a[4];
    #pragma unroll
    for (int i = 0; i < 4; ++i) {
      const int r = rg * 64 + i * 16 + l15;      // r&7 == l15&7
      a[i] = *(const f16x8*)(&x1s[r * 512 + (((kr * 4 + l4) ^ (l15 & 7)) * 8)]);
    }
    #pragma unroll
    for (int i = 0; i < 4; ++i)
      #pragma unroll
      for (int j = 0; j < 8; ++j)
        acc[i][j] = __builtin_amdgcn_mfma_f32_16x16x32_f16(a[i], bb[cur][j], acc[i][j], 0, 0, 0);
    #pragma unroll
    for (int j = 0; j < 8; ++j)
      bb[cur][j] = *(const f16x8*)(wrec + j * 8192 + (size_t)kr2 * 512);
  }

  // ---- fused epilogue: osum[row] = sum_n relu(acc + b2[n]) * W3[n]
  float part[16];
  #pragma unroll
  for (int u = 0; u < 16; ++u) part[u] = 0.f;
  #pragma unroll
  for (int j = 0; j < 8; ++j) {
    const int n = cg * 128 + j * 16 + l15;
    const float b2v = b2[n], w3v = W3[n];
    #pragma unroll
    for (int i = 0; i < 4; ++i)
      #pragma unroll
      for (int r = 0; r < 4; ++r)
        part[i * 4 + r] = fmaf(fmaxf(acc[i][j][r] + b2v, 0.f), w3v, part[i * 4 + r]);
  }
  #pragma unroll
  for (int u = 0; u < 16; ++u) {     // reduce over the 16 col-lanes (l15)
    float v = part[u];
    v += __shfl_xor(v, 1);
    v += __shfl_xor(v, 2);
    v += __shfl_xor(v, 4);
    v += __shfl_xor(v, 8);
    part[u] = v;
  }
  __syncthreads();                   // all x1s reads done before aliasing
  float* osum = (float*)x1s;         // [4 col-groups][128 rows] = 2 KiB
  if (l15 == 0) {
    #pragma unroll
    for (int i = 0; i < 4; ++i)
      #pragma unroll
      for (int r = 0; r < 4; ++r)
        osum[cg * 128 + rg * 64 + i * 16 + l4 * 4 + r] = part[i * 4 + r];
  }
  __syncthreads();
  if (t < 128) {
    float s = b3[0] + osum[t] + osum[128 + t] + osum[256 + t] + osum[384 + t];
    out[(size_t)bn * 256 + e0 + t] = s;
  }
}

extern "C" void kernel_launch(void* const* d_in, const int* in_sizes, int n_in,
                              void* d_out, int out_size, void* d_ws, size_t ws_size,
                              hipStream_t stream) {
  const float* h_all  = (const float*)d_in[0];   // (8,64,256)
  const float* e_feat = (const float*)d_in[1];   // (256,64)
  const float* W1     = (const float*)d_in[2];   // (320,512)
  const float* b1     = (const float*)d_in[3];   // (512,)
  const float* W2     = (const float*)d_in[4];   // (512,512)
  const float* b2     = (const float*)d_in[5];   // (512,)
  const float* W3     = (const float*)d_in[6];   // (512,1)
  const float* b3     = (const float*)d_in[7];   // (1,)
  float* out = (float*)d_out;                    // 131072 f32

  // workspace: hpb 512KB f16 | epb 256KB f16 | w2f 512KB f16
  unsigned short* hpb = (unsigned short*)d_ws;
  unsigned short* epb = hpb + 512 * 512;
  unsigned short* w2f = epb + 256 * 512;

  hipLaunchKernelGGL(k_prep, dim3(352), dim3(256), 0, stream,
                     h_all, e_feat, W1, b1, W2, hpb, epb, w2f);
  hipLaunchKernelGGL(k_main, dim3(1024), dim3(512), 0, stream,
                     hpb, epb, w2f, b2, W3, b3, out);
}

// Round 10
// 147.880 us; speedup vs baseline: 1.0134x; 1.0134x over previous
//
#include <hip/hip_runtime.h>
#include <hip/hip_bf16.h>
#include <hip/hip_fp16.h>

// out[bn,e] = relu(relu(hp[bn]+ep[e]+b1) @ W2 + b2) @ W3 + b3
// R14 = R11's k_main BYTE-IDENTICAL (best: 72.7us, f16 datapath, 64-row
// blocks, XOR LDS, depth-2 B ping-pong, stagger) + k_prep rewritten for
// latency: hp now 512 blocks (2 rows x 256-col half, 8 waves/CU vs 4),
// 4 independent FMA chains, unroll 4 (8 loads in flight). Isolated probe:
// total-dur delta == k_prep delta.

typedef __attribute__((ext_vector_type(8))) _Float16 f16x8;  // 8 f16 (4 VGPR)
typedef __attribute__((ext_vector_type(4))) float f32x4;     // MFMA acc

static __device__ __forceinline__ ushort2 pk_f16(float a, float b) {
  union { __half2 h; ushort2 u; } c;
  c.h = __float22half2_rn(make_float2(a, b));
  return c.u;
}

// ---------------- fused prep (608 blocks x 256 thr) ----------------
// blocks 0..511  : hpb (2 rows x 256-col half per block)
//                  hpb[r][k] = f16(sum_h h[r][h]*W1[h][k] + b1[k])
// blocks 512..543: epb rows (8/blk)  epb[e][k] = f16(sum_d e[e][d]*W1[256+d][k])
// blocks 544..607: w2f pack (64x64 W2 tile -> f16 B-frag records)
//   record(jg,ks): lane l holds W2[k = ks*32+(l>>4)*8 + u][col = jg*16+(l&15)], u=0..7
__global__ __launch_bounds__(256) void k_prep(
    const float* __restrict__ h_all, const float* __restrict__ e_feat,
    const float* __restrict__ W1, const float* __restrict__ b1,
    const float* __restrict__ W2,
    unsigned short* __restrict__ hpb, unsigned short* __restrict__ epb,
    unsigned short* __restrict__ w2f) {
  __shared__ float sm[64 * 68];   // 17408 B, reused per role
  const int t = threadIdx.x;
  const int b = blockIdx.x;

  if (b < 512) {                      // ---- hp part: 2 rows x 256 cols
    const int r0 = (b >> 1) * 2;      // row pair
    const int ch = (b & 1) * 256;     // col half
    sm[t] = h_all[(size_t)r0 * 256 + t];
    sm[256 + t] = h_all[(size_t)(r0 + 1) * 256 + t];
    __syncthreads();
    const float* hrow = sm + (t >> 7) * 256;   // this thread's row
    const int c = ch + (t & 127) * 2;          // 2 cols
    float2 a0 = make_float2(0.f, 0.f), a1 = make_float2(0.f, 0.f);
    #pragma unroll 4
    for (int k = 0; k < 256; k += 2) {         // 4 indep chains, 8 loads/unroll
      float2 w0 = *(const float2*)(W1 + (size_t)k * 512 + c);
      float2 w1 = *(const float2*)(W1 + (size_t)(k + 1) * 512 + c);
      float h0 = hrow[k], h1 = hrow[k + 1];
      a0.x = fmaf(h0, w0.x, a0.x); a0.y = fmaf(h0, w0.y, a0.y);
      a1.x = fmaf(h1, w1.x, a1.x); a1.y = fmaf(h1, w1.y, a1.y);
    }
    float2 bv = *(const float2*)(b1 + c);
    const int row = r0 + (t >> 7);
    *(ushort2*)(hpb + (size_t)row * 512 + c) =
        pk_f16(a0.x + a1.x + bv.x, a0.y + a1.y + bv.y);
  } else if (b < 544) {               // ---- ep part: 8 rows, f16 out
    const int r0 = (b - 512) * 8;
    sm[t] = e_feat[(size_t)r0 * 64 + t];
    sm[256 + t] = e_feat[(size_t)r0 * 64 + 256 + t];
    __syncthreads();
    float2 acc[8];
    #pragma unroll
    for (int i = 0; i < 8; ++i) acc[i] = make_float2(0.f, 0.f);
    for (int k = 0; k < 64; ++k) {
      float2 wv = *(const float2*)(W1 + (size_t)(256 + k) * 512 + 2 * t);
      #pragma unroll
      for (int i = 0; i < 8; ++i) {
        acc[i].x = fmaf(sm[i * 64 + k], wv.x, acc[i].x);
        acc[i].y = fmaf(sm[i * 64 + k], wv.y, acc[i].y);
      }
    }
    #pragma unroll
    for (int i = 0; i < 8; ++i)
      *(ushort2*)(epb + (size_t)(r0 + i) * 512 + 2 * t) = pk_f16(acc[i].x, acc[i].y);
  } else {                            // ---- w2f pack
    const int bb = b - 544;           // 0..63
    const int k0 = (bb >> 3) * 64;
    const int c0 = (bb & 7) * 64;
    #pragma unroll
    for (int rr = 0; rr < 4; ++rr) {
      const int row = rr * 16 + (t >> 4);
      float4 v = *(const float4*)(W2 + (size_t)(k0 + row) * 512 + c0 + (t & 15) * 4);
      *(float4*)(&sm[row * 68 + (t & 15) * 4]) = v;
    }
    __syncthreads();
    #pragma unroll
    for (int s2 = 0; s2 < 2; ++s2) {
      const int s = t * 2 + s2;       // 0..511 (8 records x 64 lanes)
      const int rec = s >> 6, l = s & 63;
      const int jg = (c0 >> 4) + (rec & 3);
      const int ksg = (k0 >> 5) + (rec >> 2);
      const int cl = (rec & 3) * 16 + (l & 15);
      const int kl = (rec >> 2) * 32 + (l >> 4) * 8;
      union { ushort2 o[4]; uint4 v; } u;
      #pragma unroll
      for (int uu = 0; uu < 4; ++uu)
        u.o[uu] = pk_f16(sm[(kl + 2 * uu) * 68 + cl], sm[(kl + 2 * uu + 1) * 68 + cl]);
      *(uint4*)(w2f + ((size_t)(jg * 16 + ksg) * 64 + l) * 8) = u.v;
    }
  }
}

// ---------------- main fused kernel (R11 verbatim) ----------------
// 2048 blocks x 256 thr. Block = 64 rows (one bn, e-quarter) x all 512 cols.
// Wave w: cols w*128..+128 (j=0..7), rows 0..63 (i=0..3).
// Depth-2 B prefetch ping-pong; per-block K stagger. All-f16 datapath.
__global__ __launch_bounds__(256, 2) void k_main(
    const unsigned short* __restrict__ hpb, const unsigned short* __restrict__ epb,
    const unsigned short* __restrict__ w2f, const float* __restrict__ b2,
    const float* __restrict__ W3, const float* __restrict__ b3,
    float* __restrict__ out) {
  __shared__ unsigned short x1s[64 * 512];   // 64 KiB, XOR-swizzled 16B chunks

  const int t = threadIdx.x;
  const int lane = t & 63;
  const int w = t >> 6;          // 0..3 -> col group (128 cols)
  const int l15 = lane & 15, l4 = lane >> 4;
  const int bn = blockIdx.x >> 2;
  const int e0 = (blockIdx.x & 3) << 6;
  const int off = (blockIdx.x * 11) & 15;   // K stagger
  const unsigned short* hprow = hpb + (size_t)bn * 512;

  // b-frag ping-pong; preload ks-slot 0 and 1 (in flight across staging)
  const unsigned short* wrec = w2f + (size_t)w * 65536 + (size_t)lane * 8;
  f16x8 bb[2][8];
  #pragma unroll
  for (int j = 0; j < 8; ++j) {
    bb[0][j] = *(const f16x8*)(wrec + j * 8192 + (size_t)off * 512);
    bb[1][j] = *(const f16x8*)(wrec + j * 8192 + (size_t)((off + 1) & 15) * 512);
  }

  // ---- stage x1 once: relu(hp + ep) -> f16 (packed pk_add/pk_max),
  // chunk' = chunk ^ (row&7)
  {
    const int kk = t & 63;          // 16B-chunk index (8 f16)
    const int rbase = t >> 6;       // 0..3
    const f16x8 fz = {0, 0, 0, 0, 0, 0, 0, 0};
    const f16x8 hv = *(const f16x8*)(hprow + kk * 8);
    #pragma unroll 2
    for (int rr = 0; rr < 16; ++rr) {
      const int r = rr * 4 + rbase;
      f16x8 ev = *(const f16x8*)(epb + (size_t)(e0 + r) * 512 + kk * 8);
      f16x8 x = hv + ev;
      x = __builtin_elementwise_max(x, fz);
      *(f16x8*)(&x1s[r * 512 + (kk ^ (r & 7)) * 8]) = x;
    }
  }
  __syncthreads();

  f32x4 acc[4][8] = {};
  #pragma unroll 4
  for (int ks = 0; ks < 16; ++ks) {
    const int cur = ks & 1;
    const int kr = (ks + off) & 15;        // this iter's k-slot
    const int kr2 = (ks + 2 + off) & 15;   // prefetch slot (wraps: dummy reload)
    f16x8 a[4];
    #pragma unroll
    for (int i = 0; i < 4; ++i) {
      const int r = i * 16 + l15;          // r&7 == l15&7
      a[i] = *(const f16x8*)(&x1s[r * 512 + (((kr * 4 + l4) ^ (l15 & 7)) * 8)]);
    }
    #pragma unroll
    for (int i = 0; i < 4; ++i)
      #pragma unroll
      for (int j = 0; j < 8; ++j)
        acc[i][j] = __builtin_amdgcn_mfma_f32_16x16x32_f16(a[i], bb[cur][j], acc[i][j], 0, 0, 0);
    #pragma unroll
    for (int j = 0; j < 8; ++j)
      bb[cur][j] = *(const f16x8*)(wrec + j * 8192 + (size_t)kr2 * 512);
  }

  // ---- fused epilogue: osum[row] = sum_n relu(acc + b2[n]) * W3[n]
  float part[16];
  #pragma unroll
  for (int u = 0; u < 16; ++u) part[u] = 0.f;
  #pragma unroll
  for (int j = 0; j < 8; ++j) {
    const int n = w * 128 + j * 16 + l15;
    const float b2v = b2[n], w3v = W3[n];
    #pragma unroll
    for (int i = 0; i < 4; ++i)
      #pragma unroll
      for (int r = 0; r < 4; ++r)
        part[i * 4 + r] = fmaf(fmaxf(acc[i][j][r] + b2v, 0.f), w3v, part[i * 4 + r]);
  }
  #pragma unroll
  for (int u = 0; u < 16; ++u) {     // reduce over the 16 col-lanes (l15)
    float v = part[u];
    v += __shfl_xor(v, 1);
    v += __shfl_xor(v, 2);
    v += __shfl_xor(v, 4);
    v += __shfl_xor(v, 8);
    part[u] = v;
  }
  __syncthreads();                   // all x1s reads done before aliasing
  float* osum = (float*)x1s;         // [4 col-groups][64 rows]
  if (l15 == 0) {
    #pragma unroll
    for (int i = 0; i < 4; ++i)
      #pragma unroll
      for (int r = 0; r < 4; ++r)
        osum[w * 64 + i * 16 + l4 * 4 + r] = part[i * 4 + r];
  }
  __syncthreads();
  if (t < 64) {
    float s = b3[0] + osum[t] + osum[64 + t] + osum[128 + t] + osum[192 + t];
    out[(size_t)bn * 256 + e0 + t] = s;
  }
}

extern "C" void kernel_launch(void* const* d_in, const int* in_sizes, int n_in,
                              void* d_out, int out_size, void* d_ws, size_t ws_size,
                              hipStream_t stream) {
  const float* h_all  = (const float*)d_in[0];   // (8,64,256)
  const float* e_feat = (const float*)d_in[1];   // (256,64)
  const float* W1     = (const float*)d_in[2];   // (320,512)
  const float* b1     = (const float*)d_in[3];   // (512,)
  const float* W2     = (const float*)d_in[4];   // (512,512)
  const float* b2     = (const float*)d_in[5];   // (512,)
  const float* W3     = (const float*)d_in[6];   // (512,1)
  const float* b3     = (const float*)d_in[7];   // (1,)
  float* out = (float*)d_out;                    // 131072 f32

  // workspace: hpb 512KB f16 | epb 256KB f16 | w2f 512KB f16
  unsigned short* hpb = (unsigned short*)d_ws;
  unsigned short* epb = hpb + 512 * 512;
  unsigned short* w2f = epb + 256 * 512;

  hipLaunchKernelGGL(k_prep, dim3(608), dim3(256), 0, stream,
                     h_all, e_feat, W1, b1, W2, hpb, epb, w2f);
  hipLaunchKernelGGL(k_main, dim3(2048), dim3(256), 0, stream,
                     hpb, epb, w2f, b2, W3, b3, out);
}

// Round 11
// 140.701 us; speedup vs baseline: 1.0651x; 1.0510x over previous
//
#include <hip/hip_runtime.h>
#include <hip/hip_bf16.h>
#include <hip/hip_fp16.h>

// out[bn,e] = relu(relu(hp[bn]+ep[e]+b1) @ W2 + b2) @ W3 + b3
// R15 = R11 (best: 144.3 total / 72.7 k_main; f16 datapath, 64-row blocks,
// XOR LDS, depth-2 B ping-pong, K stagger, 352-blk k_prep) + two contained
// k_main edits: (1) s_setprio(1) around the MFMA nest (T5 — independent
// blocks at staggered phases = the attn-like regime where it measured +4-7%);
// (2) peel last 2 K-steps to drop the 12.5% dummy B reloads.

typedef __attribute__((ext_vector_type(8))) _Float16 f16x8;  // 8 f16 (4 VGPR)
typedef __attribute__((ext_vector_type(4))) float f32x4;     // MFMA acc

static __device__ __forceinline__ ushort2 pk_f16(float a, float b) {
  union { __half2 h; ushort2 u; } c;
  c.h = __float22half2_rn(make_float2(a, b));
  return c.u;
}

// ---------------- fused prep (352 blocks x 256 thr) ----------------
// blocks 0..255  : hpb rows (2/blk)  hpb[r][k] = f16(sum_h h[r][h]*W1[h][k] + b1[k])
// blocks 256..287: epb rows (8/blk)  epb[e][k] = f16(sum_d e[e][d]*W1[256+d][k])
// blocks 288..351: w2f pack (64x64 W2 tile -> f16 B-frag records)
//   record(jg,ks): lane l holds W2[k = ks*32+(l>>4)*8 + u][col = jg*16+(l&15)], u=0..7
__global__ __launch_bounds__(256) void k_prep(
    const float* __restrict__ h_all, const float* __restrict__ e_feat,
    const float* __restrict__ W1, const float* __restrict__ b1,
    const float* __restrict__ W2,
    unsigned short* __restrict__ hpb, unsigned short* __restrict__ epb,
    unsigned short* __restrict__ w2f) {
  __shared__ float sm[64 * 68];   // 17408 B, reused per role
  const int t = threadIdx.x;
  const int b = blockIdx.x;

  if (b < 256) {                      // ---- hp part: 2 rows, f16 out
    const int r0 = b * 2;
    float (*hs)[256] = (float(*)[256])sm;
    hs[0][t] = h_all[(size_t)r0 * 256 + t];
    hs[1][t] = h_all[(size_t)(r0 + 1) * 256 + t];
    __syncthreads();
    float2 a0 = make_float2(0.f, 0.f), a1 = make_float2(0.f, 0.f);
    #pragma unroll 2
    for (int k = 0; k < 256; k += 4) {
      float2 w0 = *(const float2*)(W1 + (size_t)k * 512 + 2 * t);
      float2 w1 = *(const float2*)(W1 + (size_t)(k + 1) * 512 + 2 * t);
      float2 w2v = *(const float2*)(W1 + (size_t)(k + 2) * 512 + 2 * t);
      float2 w3v = *(const float2*)(W1 + (size_t)(k + 3) * 512 + 2 * t);
      float h00 = hs[0][k], h01 = hs[0][k + 1], h02 = hs[0][k + 2], h03 = hs[0][k + 3];
      float h10 = hs[1][k], h11 = hs[1][k + 1], h12 = hs[1][k + 2], h13 = hs[1][k + 3];
      a0.x = fmaf(h00, w0.x, a0.x); a0.y = fmaf(h00, w0.y, a0.y);
      a1.x = fmaf(h10, w0.x, a1.x); a1.y = fmaf(h10, w0.y, a1.y);
      a0.x = fmaf(h01, w1.x, a0.x); a0.y = fmaf(h01, w1.y, a0.y);
      a1.x = fmaf(h11, w1.x, a1.x); a1.y = fmaf(h11, w1.y, a1.y);
      a0.x = fmaf(h02, w2v.x, a0.x); a0.y = fmaf(h02, w2v.y, a0.y);
      a1.x = fmaf(h12, w2v.x, a1.x); a1.y = fmaf(h12, w2v.y, a1.y);
      a0.x = fmaf(h03, w3v.x, a0.x); a0.y = fmaf(h03, w3v.y, a0.y);
      a1.x = fmaf(h13, w3v.x, a1.x); a1.y = fmaf(h13, w3v.y, a1.y);
    }
    float2 bv = *(const float2*)(b1 + 2 * t);
    *(ushort2*)(hpb + (size_t)r0 * 512 + 2 * t) = pk_f16(a0.x + bv.x, a0.y + bv.y);
    *(ushort2*)(hpb + (size_t)(r0 + 1) * 512 + 2 * t) = pk_f16(a1.x + bv.x, a1.y + bv.y);
  } else if (b < 288) {               // ---- ep part: 8 rows, f16 out
    const int r0 = (b - 256) * 8;
    sm[t] = e_feat[(size_t)r0 * 64 + t];
    sm[256 + t] = e_feat[(size_t)r0 * 64 + 256 + t];
    __syncthreads();
    float2 acc[8];
    #pragma unroll
    for (int i = 0; i < 8; ++i) acc[i] = make_float2(0.f, 0.f);
    for (int k = 0; k < 64; ++k) {
      float2 wv = *(const float2*)(W1 + (size_t)(256 + k) * 512 + 2 * t);
      #pragma unroll
      for (int i = 0; i < 8; ++i) {
        acc[i].x = fmaf(sm[i * 64 + k], wv.x, acc[i].x);
        acc[i].y = fmaf(sm[i * 64 + k], wv.y, acc[i].y);
      }
    }
    #pragma unroll
    for (int i = 0; i < 8; ++i)
      *(ushort2*)(epb + (size_t)(r0 + i) * 512 + 2 * t) = pk_f16(acc[i].x, acc[i].y);
  } else {                            // ---- w2f pack
    const int bb = b - 288;           // 0..63
    const int k0 = (bb >> 3) * 64;
    const int c0 = (bb & 7) * 64;
    #pragma unroll
    for (int rr = 0; rr < 4; ++rr) {
      const int row = rr * 16 + (t >> 4);
      float4 v = *(const float4*)(W2 + (size_t)(k0 + row) * 512 + c0 + (t & 15) * 4);
      *(float4*)(&sm[row * 68 + (t & 15) * 4]) = v;
    }
    __syncthreads();
    #pragma unroll
    for (int s2 = 0; s2 < 2; ++s2) {
      const int s = t * 2 + s2;       // 0..511 (8 records x 64 lanes)
      const int rec = s >> 6, l = s & 63;
      const int jg = (c0 >> 4) + (rec & 3);
      const int ksg = (k0 >> 5) + (rec >> 2);
      const int cl = (rec & 3) * 16 + (l & 15);
      const int kl = (rec >> 2) * 32 + (l >> 4) * 8;
      union { ushort2 o[4]; uint4 v; } u;
      #pragma unroll
      for (int uu = 0; uu < 4; ++uu)
        u.o[uu] = pk_f16(sm[(kl + 2 * uu) * 68 + cl], sm[(kl + 2 * uu + 1) * 68 + cl]);
      *(uint4*)(w2f + ((size_t)(jg * 16 + ksg) * 64 + l) * 8) = u.v;
    }
  }
}

// ---------------- main fused kernel ----------------
// 2048 blocks x 256 thr. Block = 64 rows (one bn, e-quarter) x all 512 cols.
// Wave w: cols w*128..+128 (j=0..7), rows 0..63 (i=0..3).
// Depth-2 B prefetch ping-pong; per-block K stagger. All-f16 datapath.
// setprio around MFMA nest; last 2 K-steps peeled (no dummy B reloads).
__global__ __launch_bounds__(256, 2) void k_main(
    const unsigned short* __restrict__ hpb, const unsigned short* __restrict__ epb,
    const unsigned short* __restrict__ w2f, const float* __restrict__ b2,
    const float* __restrict__ W3, const float* __restrict__ b3,
    float* __restrict__ out) {
  __shared__ unsigned short x1s[64 * 512];   // 64 KiB, XOR-swizzled 16B chunks

  const int t = threadIdx.x;
  const int lane = t & 63;
  const int w = t >> 6;          // 0..3 -> col group (128 cols)
  const int l15 = lane & 15, l4 = lane >> 4;
  const int bn = blockIdx.x >> 2;
  const int e0 = (blockIdx.x & 3) << 6;
  const int off = (blockIdx.x * 11) & 15;   // K stagger
  const unsigned short* hprow = hpb + (size_t)bn * 512;

  // b-frag ping-pong; preload ks-slot 0 and 1 (in flight across staging)
  const unsigned short* wrec = w2f + (size_t)w * 65536 + (size_t)lane * 8;
  f16x8 bb[2][8];
  #pragma unroll
  for (int j = 0; j < 8; ++j) {
    bb[0][j] = *(const f16x8*)(wrec + j * 8192 + (size_t)off * 512);
    bb[1][j] = *(const f16x8*)(wrec + j * 8192 + (size_t)((off + 1) & 15) * 512);
  }

  // ---- stage x1 once: relu(hp + ep) -> f16 (packed pk_add/pk_max),
  // chunk' = chunk ^ (row&7)
  {
    const int kk = t & 63;          // 16B-chunk index (8 f16)
    const int rbase = t >> 6;       // 0..3
    const f16x8 fz = {0, 0, 0, 0, 0, 0, 0, 0};
    const f16x8 hv = *(const f16x8*)(hprow + kk * 8);
    #pragma unroll 2
    for (int rr = 0; rr < 16; ++rr) {
      const int r = rr * 4 + rbase;
      f16x8 ev = *(const f16x8*)(epb + (size_t)(e0 + r) * 512 + kk * 8);
      f16x8 x = hv + ev;
      x = __builtin_elementwise_max(x, fz);
      *(f16x8*)(&x1s[r * 512 + (kk ^ (r & 7)) * 8]) = x;
    }
  }
  __syncthreads();

  f32x4 acc[4][8] = {};
  // steady steps 0..13: A-reads, MFMA nest (prio-boosted), B prefetch for ks+2
  #pragma unroll 2
  for (int ks = 0; ks < 14; ++ks) {
    const int cur = ks & 1;
    const int kr = (ks + off) & 15;        // this iter's k-slot
    const int krb = (ks + 2 + off) & 15;   // prefetch slot (always valid here)
    f16x8 a[4];
    #pragma unroll
    for (int i = 0; i < 4; ++i) {
      const int r = i * 16 + l15;          // r&7 == l15&7
      a[i] = *(const f16x8*)(&x1s[r * 512 + (((kr * 4 + l4) ^ (l15 & 7)) * 8)]);
    }
    __builtin_amdgcn_s_setprio(1);
    #pragma unroll
    for (int i = 0; i < 4; ++i)
      #pragma unroll
      for (int j = 0; j < 8; ++j)
        acc[i][j] = __builtin_amdgcn_mfma_f32_16x16x32_f16(a[i], bb[cur][j], acc[i][j], 0, 0, 0);
    __builtin_amdgcn_s_setprio(0);
    #pragma unroll
    for (int j = 0; j < 8; ++j)
      bb[cur][j] = *(const f16x8*)(wrec + j * 8192 + (size_t)krb * 512);
  }
  // tail steps 14,15: consume the last prefetched slots, no B reloads
  #pragma unroll
  for (int ks = 14; ks < 16; ++ks) {
    const int cur = ks & 1;
    const int kr = (ks + off) & 15;
    f16x8 a[4];
    #pragma unroll
    for (int i = 0; i < 4; ++i) {
      const int r = i * 16 + l15;
      a[i] = *(const f16x8*)(&x1s[r * 512 + (((kr * 4 + l4) ^ (l15 & 7)) * 8)]);
    }
    __builtin_amdgcn_s_setprio(1);
    #pragma unroll
    for (int i = 0; i < 4; ++i)
      #pragma unroll
      for (int j = 0; j < 8; ++j)
        acc[i][j] = __builtin_amdgcn_mfma_f32_16x16x32_f16(a[i], bb[cur][j], acc[i][j], 0, 0, 0);
    __builtin_amdgcn_s_setprio(0);
  }

  // ---- fused epilogue: osum[row] = sum_n relu(acc + b2[n]) * W3[n]
  float part[16];
  #pragma unroll
  for (int u = 0; u < 16; ++u) part[u] = 0.f;
  #pragma unroll
  for (int j = 0; j < 8; ++j) {
    const int n = w * 128 + j * 16 + l15;
    const float b2v = b2[n], w3v = W3[n];
    #pragma unroll
    for (int i = 0; i < 4; ++i)
      #pragma unroll
      for (int r = 0; r < 4; ++r)
        part[i * 4 + r] = fmaf(fmaxf(acc[i][j][r] + b2v, 0.f), w3v, part[i * 4 + r]);
  }
  #pragma unroll
  for (int u = 0; u < 16; ++u) {     // reduce over the 16 col-lanes (l15)
    float v = part[u];
    v += __shfl_xor(v, 1);
    v += __shfl_xor(v, 2);
    v += __shfl_xor(v, 4);
    v += __shfl_xor(v, 8);
    part[u] = v;
  }
  __syncthreads();                   // all x1s reads done before aliasing
  float* osum = (float*)x1s;         // [4 col-groups][64 rows]
  if (l15 == 0) {
    #pragma unroll
    for (int i = 0; i < 4; ++i)
      #pragma unroll
      for (int r = 0; r < 4; ++r)
        osum[w * 64 + i * 16 + l4 * 4 + r] = part[i * 4 + r];
  }
  __syncthreads();
  if (t < 64) {
    float s = b3[0] + osum[t] + osum[64 + t] + osum[128 + t] + osum[192 + t];
    out[(size_t)bn * 256 + e0 + t] = s;
  }
}

extern "C" void kernel_launch(void* const* d_in, const int* in_sizes, int n_in,
                              void* d_out, int out_size, void* d_ws, size_t ws_size,
                              hipStream_t stream) {
  const float* h_all  = (const float*)d_in[0];   // (8,64,256)
  const float* e_feat = (const float*)d_in[1];   // (256,64)
  const float* W1     = (const float*)d_in[2];   // (320,512)
  const float* b1     = (const float*)d_in[3];   // (512,)
  const float* W2     = (const float*)d_in[4];   // (512,512)
  const float* b2     = (const float*)d_in[5];   // (512,)
  const float* W3     = (const float*)d_in[6];   // (512,1)
  const float* b3     = (const float*)d_in[7];   // (1,)
  float* out = (float*)d_out;                    // 131072 f32

  // workspace: hpb 512KB f16 | epb 256KB f16 | w2f 512KB f16
  unsigned short* hpb = (unsigned short*)d_ws;
  unsigned short* epb = hpb + 512 * 512;
  unsigned short* w2f = epb + 256 * 512;

  hipLaunchKernelGGL(k_prep, dim3(352), dim3(256), 0, stream,
                     h_all, e_feat, W1, b1, W2, hpb, epb, w2f);
  hipLaunchKernelGGL(k_main, dim3(2048), dim3(256), 0, stream,
                     hpb, epb, w2f, b2, W3, b3, out);
}